// Round 15
// baseline (108.412 us; speedup 1.0000x reference)
//
#include <hip/hip_runtime.h>
#include <hip/hip_bf16.h>

// MHA forward: x[2,2048,1024] fp32, Wq/Wk/Wv/Wo [1024,1024] fp32, b_o[1024]
// out = softmax_causal((xWq)(xWk)^T / 8) (xWv) Wo + b_o   (16 heads, d=64)

typedef __bf16 bf16x8 __attribute__((ext_vector_type(8)));
typedef __bf16 bf16x4 __attribute__((ext_vector_type(4)));
typedef float  f32x4  __attribute__((ext_vector_type(4)));

typedef __attribute__((address_space(1))) void gas_void;
typedef __attribute__((address_space(3))) void las_void;

__device__ __forceinline__ void gload_lds16(const void* g, void* l) {
  __builtin_amdgcn_global_load_lds((gas_void*)g, (las_void*)l, 16, 0, 0);
}

#define FULL_DRAIN() asm volatile("s_waitcnt vmcnt(0) lgkmcnt(0)" ::: "memory")
#define SCHED_FENCE() __builtin_amdgcn_sched_barrier(0)

// Q scale: 1/sqrt(64) * log2(e)  (softmax done in exp2 domain)
#define QSCALE 0.18033688011112042f

// ---------------- prep: fp32 -> bf16 convert ----------------
__global__ void cvt_f32_bf16_k(const float* __restrict__ in, __bf16* __restrict__ out, int n4) {
  int i = blockIdx.x * 256 + threadIdx.x;
  if (i >= n4) return;
  float4 v = ((const float4*)in)[i];
  bf16x4 o = { (__bf16)v.x, (__bf16)v.y, (__bf16)v.z, (__bf16)v.w };
  ((bf16x4*)out)[i] = o;
}

// ---------------- prep: 4x W[k][n] fp32 -> Wt[n][k] bf16 (one launch) ----------------
__global__ void transpose_w4_k(const float* __restrict__ Wq, const float* __restrict__ Wk,
                               const float* __restrict__ Wv, const float* __restrict__ Wo,
                               __bf16* __restrict__ wtqkv, __bf16* __restrict__ wot) {
  __shared__ float tile[32][33];
  const int z = blockIdx.z;
  const float* in = z == 0 ? Wq : z == 1 ? Wk : z == 2 ? Wv : Wo;
  __bf16* out = z < 3 ? wtqkv + (size_t)z * 1048576 : wot;
  const int bx = blockIdx.x, by = blockIdx.y;
  const int tx = threadIdx.x, ty = threadIdx.y; // 32 x 8
#pragma unroll
  for (int i = 0; i < 4; ++i)
    tile[ty + i * 8][tx] = in[(by * 32 + ty + i * 8) * 1024 + bx * 32 + tx];
  __syncthreads();
#pragma unroll
  for (int i = 0; i < 4; ++i)
    out[(size_t)(bx * 32 + ty + i * 8) * 1024 + by * 32 + tx] = (__bf16)tile[tx][ty + i * 8];
}

// swizzled read from a [rows][32] bf16 tile (64B rows): byte ^= ((row>>1)&3)<<4
__device__ __forceinline__ bf16x8 lds_swz32(const __bf16* base, int row, int cb) {
  const char* p = (const char*)base + row * 64 + (cb ^ (((row >> 1) & 3) << 4));
  return *(const bf16x8*)p;
}

// ---------------- QKV GEMM: 128x128 tile, 3-buffer counted-vmcnt ----------------
// Plain dim3(32,24) grid (round-13 lesson: XCD remap hurt panel locality).
__global__ __launch_bounds__(256) void gemm_qkv_k(
    const __bf16* __restrict__ A, const __bf16* __restrict__ Bt,
    __bf16* __restrict__ qo, __bf16* __restrict__ ko, __bf16* __restrict__ vo)
{
  __shared__ __align__(16) __bf16 As[3][4096];
  __shared__ __align__(16) __bf16 Bs[3][4096];

  const int bm = blockIdx.x, bn = blockIdx.y;

  const int t = threadIdx.x;
  const int l = t & 63;
  const int w = t >> 6;
  const int wr = w >> 1, wc = w & 1;
  const int lr = l & 15;
  const int lkb = (l >> 4) * 16;

  const int swz_el = ((t & 3) * 8) ^ (((t >> 3) & 3) << 3);
  const __bf16* a0 = A + (size_t)(bm * 128 + (t >> 2)) * 1024 + swz_el;
  const __bf16* b0 = Bt + (size_t)(bn * 128 + (t >> 2)) * 1024 + swz_el;

  f32x4 acc[4][4] = {};

#define STAGE(kt_, buf_)                                          \
  do {                                                            \
    const int k0_ = (kt_) * 32;                                   \
    gload_lds16(a0 + k0_, As[buf_] + t * 8);                      \
    gload_lds16(a0 + 64 * 1024 + k0_, As[buf_] + 2048 + t * 8);   \
    gload_lds16(b0 + k0_, Bs[buf_] + t * 8);                      \
    gload_lds16(b0 + 64 * 1024 + k0_, Bs[buf_] + 2048 + t * 8);   \
  } while (0)

  STAGE(0, 0);
  STAGE(1, 1);
  SCHED_FENCE();
  asm volatile("s_waitcnt vmcnt(4)" ::: "memory");
  __builtin_amdgcn_s_barrier();
  SCHED_FENCE();

  int bc = 0, bs = 2;
  for (int kt = 0; kt < 32; ++kt) {
    if (kt < 30) STAGE(kt + 2, bs);
    SCHED_FENCE();

    bf16x8 af[4], bfr[4];
#pragma unroll
    for (int m = 0; m < 4; ++m)
      af[m] = lds_swz32(As[bc], wr * 64 + m * 16 + lr, lkb);
#pragma unroll
    for (int n = 0; n < 4; ++n)
      bfr[n] = lds_swz32(Bs[bc], wc * 64 + n * 16 + lr, lkb);
#pragma unroll
    for (int m = 0; m < 4; ++m)
#pragma unroll
      for (int n = 0; n < 4; ++n)
        acc[m][n] = __builtin_amdgcn_mfma_f32_16x16x32_bf16(af[m], bfr[n], acc[m][n], 0, 0, 0);

    SCHED_FENCE();
    if (kt < 30) asm volatile("s_waitcnt vmcnt(4)" ::: "memory");
    else         asm volatile("s_waitcnt vmcnt(0)" ::: "memory");
    __builtin_amdgcn_s_barrier();
    SCHED_FENCE();
    bc = (bc == 2) ? 0 : bc + 1;
    bs = (bs == 2) ? 0 : bs + 1;
  }
#undef STAGE

#pragma unroll
  for (int m = 0; m < 4; ++m) {
    const int rg = bm * 128 + wr * 64 + m * 16 + (l >> 4) * 4;
#pragma unroll
    for (int n = 0; n < 4; ++n) {
      const int cg = bn * 128 + wc * 64 + n * 16 + lr;
      const int proj = cg >> 10, within = cg & 1023;
      const int h = within >> 6, d = within & 63;
#pragma unroll
      for (int r = 0; r < 4; ++r) {
        const int row = rg + r;
        const int b = row >> 11, pos = row & 2047;
        const int bh = b * 16 + h;
        const float v = acc[m][n][r];
        if (proj == 0) {
          qo[((size_t)bh * 2048 + pos) * 64 + d] = (__bf16)(v * QSCALE);
        } else if (proj == 1) {
          const int tile = pos >> 6, rr = pos & 63;
          const int off = rr * 128 + ((d * 2) ^ ((rr & 7) << 4));
          *(__bf16*)((char*)ko + ((size_t)bh * 32 + tile) * 8192 + off) = (__bf16)v;
        } else {
          const int tile = pos >> 6, cc = pos & 63;
          const int off = d * 128 + ((cc * 2) ^ ((d & 7) << 4));
          *(__bf16*)((char*)vo + ((size_t)bh * 32 + tile) * 8192 + off) = (__bf16)v;
        }
      }
    }
  }
}

// ---------------- out GEMM: 128x64 tile, 2 blocks/CU, 3-buffer ----------------
__global__ __launch_bounds__(256) void gemm_out_k(
    const __bf16* __restrict__ A, const __bf16* __restrict__ Bt,
    float* __restrict__ outf, const float* __restrict__ bias)
{
  __shared__ __align__(16) __bf16 As[3][4096];   // 128x32 per buf
  __shared__ __align__(16) __bf16 Bs[3][2048];   // 64x32 per buf

  const int bid = blockIdx.x;
  const int bm = bid & 31, bn = bid >> 5;        // 32 x 16, plain order

  const int t = threadIdx.x;
  const int l = t & 63;
  const int w = t >> 6;
  const int wr = w >> 1, wc = w & 1;             // 2M x 2N
  const int lr = l & 15;
  const int lkb = (l >> 4) * 16;

  const int swz_el = ((t & 3) * 8) ^ (((t >> 3) & 3) << 3);
  const __bf16* a0 = A + (size_t)(bm * 128 + (t >> 2)) * 1024 + swz_el;
  const __bf16* b0 = Bt + (size_t)(bn * 64 + (t >> 2)) * 1024 + swz_el;

  f32x4 acc[4][2] = {};

#define STAGE(kt_, buf_)                                          \
  do {                                                            \
    const int k0_ = (kt_) * 32;                                   \
    gload_lds16(a0 + k0_, As[buf_] + t * 8);                      \
    gload_lds16(a0 + 64 * 1024 + k0_, As[buf_] + 2048 + t * 8);   \
    gload_lds16(b0 + k0_, Bs[buf_] + t * 8);                      \
  } while (0)

  STAGE(0, 0);
  STAGE(1, 1);
  SCHED_FENCE();
  asm volatile("s_waitcnt vmcnt(3)" ::: "memory");
  __builtin_amdgcn_s_barrier();
  SCHED_FENCE();

  int bc = 0, bs = 2;
  for (int kt = 0; kt < 32; ++kt) {
    if (kt < 30) STAGE(kt + 2, bs);
    SCHED_FENCE();

    bf16x8 af[4], bfr[2];
#pragma unroll
    for (int m = 0; m < 4; ++m)
      af[m] = lds_swz32(As[bc], wr * 64 + m * 16 + lr, lkb);
#pragma unroll
    for (int n = 0; n < 2; ++n)
      bfr[n] = lds_swz32(Bs[bc], wc * 32 + n * 16 + lr, lkb);
#pragma unroll
    for (int m = 0; m < 4; ++m)
#pragma unroll
      for (int n = 0; n < 2; ++n)
        acc[m][n] = __builtin_amdgcn_mfma_f32_16x16x32_bf16(af[m], bfr[n], acc[m][n], 0, 0, 0);

    SCHED_FENCE();
    if (kt < 30) asm volatile("s_waitcnt vmcnt(3)" ::: "memory");
    else         asm volatile("s_waitcnt vmcnt(0)" ::: "memory");
    __builtin_amdgcn_s_barrier();
    SCHED_FENCE();
    bc = (bc == 2) ? 0 : bc + 1;
    bs = (bs == 2) ? 0 : bs + 1;
  }
#undef STAGE

#pragma unroll
  for (int m = 0; m < 4; ++m) {
    const int rg = bm * 128 + wr * 64 + m * 16 + (l >> 4) * 4;
#pragma unroll
    for (int n = 0; n < 2; ++n) {
      const int cg = bn * 64 + wc * 32 + n * 16 + lr;
#pragma unroll
      for (int r = 0; r < 4; ++r)
        outf[(size_t)(rg + r) * 1024 + cg] = acc[m][n][r] + bias[cg];
    }
  }
}

// swizzled LDS fragment read: tile row stride 128 B, byte ^= (row&7)<<4
__device__ __forceinline__ bf16x8 lds_swz(const __bf16* base, int row, int cb) {
  const char* p = (const char*)base + row * 128 + (cb ^ ((row & 7) << 4));
  return *(const bf16x8*)p;
}

// ---------------- flash attention (causal), head_dim=64 ----------------
// 512 blocks x 512 threads. q-tile 128, kv-tile 64. 8 waves as (qb = w&3:
// 32 q-rows) x (kvh = w>>2: 32-kv half). Fixed-shift exp2 softmax; per-wave
// partials merged once after the kv loop via LDS exchange.
// Round-15 change: 3-buffer K/V with COUNTED vmcnt(2) at the iter boundary
// (the per-iter FULL_DRAIN since round 8 was draining the same-iter prefetch
// -> synchronous staging). Protocol isomorphic to the proven GEMM loop.
// V-fragment reads hoisted before the exp/P-store section so their latency
// hides under QK^T+exp.
__global__ __launch_bounds__(512) void attn_fwd_k(
    const __bf16* __restrict__ Q, const __bf16* __restrict__ K,
    const __bf16* __restrict__ V, __bf16* __restrict__ ctx)
{
  __shared__ __align__(16) char smem[70144];
  __bf16* Kbuf = (__bf16*)smem;                    // [3][4096] bf16, 24KB
  __bf16* Vbuf = (__bf16*)(smem + 24576);          // [3][4096] bf16, 24KB
  __bf16* PsB  = (__bf16*)(smem + 49152);          // [8][32*40] bf16, 20KB
  float*  LsX  = (float*)(smem + 69632);           // [4][32] f32, 512B
  float*  xch  = (float*)smem;                     // 8192 f32 (aliases K/V bufs)

  const int n = blockIdx.x;
  const int bh = (n & 255) >> 3;
  const int pp = n & 7;
  const int qt = (n >> 8) ? pp : 15 - pp;   // q-tile of 128 rows
  const int nkt = 2 * qt + 2;               // kv tiles of 64 (always >= 2)

  const int t = threadIdx.x, l = t & 63, w = t >> 6;   // w = 0..7
  const int lr = l & 15, lg = l >> 4;
  const int qb = w & 3;
  const int kvh = w >> 2;

  const __bf16* qptr = Q + (size_t)bh * 131072;
  const __bf16* kptr = K + (size_t)bh * 131072;
  const __bf16* vptr = V + (size_t)bh * 131072;
  __bf16* Ps = PsB + w * 1280;

  bf16x8 qf[2][2];
#pragma unroll
  for (int m = 0; m < 2; ++m)
#pragma unroll
    for (int h2 = 0; h2 < 2; ++h2)
      qf[m][h2] = *(const bf16x8*)(qptr + (size_t)(qt * 128 + qb * 32 + m * 16 + lr) * 64 + h2 * 32 + lg * 8);

  f32x4 o[2][4] = {};
  f32x4 lsum[2] = {};

#define ASTAGE(kt_, buf_)                                                  \
  do {                                                                     \
    gload_lds16(kptr + (kt_) * 4096 + t * 8, Kbuf + (buf_) * 4096 + t * 8); \
    gload_lds16(vptr + (kt_) * 4096 + t * 8, Vbuf + (buf_) * 4096 + t * 8); \
  } while (0)

  // prologue: tiles 0 and 1 in flight; retire tile 0, keep tile 1 flying
  ASTAGE(0, 0);
  ASTAGE(1, 1);
  SCHED_FENCE();
  asm volatile("s_waitcnt vmcnt(2)" ::: "memory");
  __builtin_amdgcn_s_barrier();
  SCHED_FENCE();

  int bc = 0, bs = 2;
  for (int kt = 0; kt < nkt; ++kt) {
    if (kt + 2 < nkt) ASTAGE(kt + 2, bs);
    SCHED_FENCE();
    const __bf16* Kb = Kbuf + bc * 4096;
    const __bf16* Vb = Vbuf + bc * 4096;

    // K frags (QK^T waits only these; V frags stay outstanding)
    bf16x8 kf[2][2];
#pragma unroll
    for (int ng = 0; ng < 2; ++ng)
#pragma unroll
      for (int h2 = 0; h2 < 2; ++h2)
        kf[ng][h2] = lds_swz(Kb, kvh * 32 + ng * 16 + lr, h2 * 64 + lg * 16);
    // V frags hoisted: latency hides under QK^T + exp section
    bf16x8 vf[4];
#pragma unroll
    for (int ngd = 0; ngd < 4; ++ngd)
      vf[ngd] = lds_swz(Vb, ngd * 16 + lr, kvh * 64 + lg * 16);

    f32x4 s[2][2];
#pragma unroll
    for (int m = 0; m < 2; ++m)
#pragma unroll
      for (int ng = 0; ng < 2; ++ng) {
        f32x4 z = {};
        z = __builtin_amdgcn_mfma_f32_16x16x32_bf16(qf[m][0], kf[ng][0], z, 0, 0, 0);
        s[m][ng] = __builtin_amdgcn_mfma_f32_16x16x32_bf16(qf[m][1], kf[ng][1], z, 0, 0, 0);
      }

    if (kt >= 2 * qt) {  // diagonal region: causal mask
#pragma unroll
      for (int m = 0; m < 2; ++m) {
        const int qpos = qt * 128 + qb * 32 + m * 16 + lg * 4;
#pragma unroll
        for (int ng = 0; ng < 2; ++ng) {
          const int kv = kt * 64 + kvh * 32 + ng * 16 + lr;
#pragma unroll
          for (int r = 0; r < 4; ++r)
            if (kv > qpos + r) s[m][ng][r] = -1e30f;
        }
      }
    }

    // P = exp2(S) (fixed shift), accumulate partial sums, stage P
#pragma unroll
    for (int m = 0; m < 2; ++m)
#pragma unroll
      for (int ng = 0; ng < 2; ++ng)
#pragma unroll
        for (int r = 0; r < 4; ++r) {
          const float p = __builtin_amdgcn_exp2f(s[m][ng][r]);
          lsum[m][r] += p;
          Ps[(m * 16 + lg * 4 + r) * 40 + ng * 16 + lr] = (__bf16)p;
        }

    asm volatile("s_waitcnt lgkmcnt(0)" ::: "memory");
    SCHED_FENCE();

    bf16x8 pf[2];
#pragma unroll
    for (int m = 0; m < 2; ++m)
      pf[m] = *(const bf16x8*)(Ps + (m * 16 + lr) * 40 + lg * 8);
#pragma unroll
    for (int m = 0; m < 2; ++m)
#pragma unroll
      for (int ngd = 0; ngd < 4; ++ngd)
        o[m][ngd] = __builtin_amdgcn_mfma_f32_16x16x32_bf16(pf[m], vf[ngd], o[m][ngd], 0, 0, 0);

    SCHED_FENCE();
    // counted wait: tile kt+1's 2 loads retired; tile kt+2's stay in flight
    if (kt + 2 < nkt) asm volatile("s_waitcnt vmcnt(2)" ::: "memory");
    else              asm volatile("s_waitcnt vmcnt(0)" ::: "memory");
    __builtin_amdgcn_s_barrier();
    SCHED_FENCE();
    bc = (bc == 2) ? 0 : bc + 1;
    bs = (bs == 2) ? 0 : bs + 1;
  }
#undef ASTAGE

  // finish per-lane partial row sums: tree over the 16 lr lanes
#pragma unroll
  for (int m = 0; m < 2; ++m)
#pragma unroll
    for (int r = 0; r < 4; ++r) {
      float v = lsum[m][r];
      v += __shfl_xor(v, 1);
      v += __shfl_xor(v, 2);
      v += __shfl_xor(v, 4);
      v += __shfl_xor(v, 8);
      lsum[m][r] = v;
    }

  // cross-wave merge of the two kv-halves (K/V staging dead; xch aliases it)
  if (kvh == 1) {
#pragma unroll
    for (int m = 0; m < 2; ++m)
#pragma unroll
      for (int ngd = 0; ngd < 4; ++ngd)
#pragma unroll
        for (int r = 0; r < 4; ++r)
          xch[qb * 2048 + (m * 16 + lg * 4 + r) * 64 + ngd * 16 + lr] = o[m][ngd][r];
    if (lr == 0) {
#pragma unroll
      for (int m = 0; m < 2; ++m)
#pragma unroll
        for (int r = 0; r < 4; ++r)
          LsX[qb * 32 + m * 16 + lg * 4 + r] = lsum[m][r];
    }
  }
  FULL_DRAIN();
  __syncthreads();
  SCHED_FENCE();

  if (kvh == 0) {
    const int b_ = bh >> 4, h = bh & 15;
#pragma unroll
    for (int m = 0; m < 2; ++m)
#pragma unroll
      for (int r = 0; r < 4; ++r) {
        const float sum = lsum[m][r] + LsX[qb * 32 + m * 16 + lg * 4 + r];
        const float inv = 1.0f / sum;
        const int pos = qt * 128 + qb * 32 + m * 16 + lg * 4 + r;
#pragma unroll
        for (int ngd = 0; ngd < 4; ++ngd) {
          const float val = o[m][ngd][r] +
              xch[qb * 2048 + (m * 16 + lg * 4 + r) * 64 + ngd * 16 + lr];
          ctx[((size_t)(b_ * 2048 + pos)) * 1024 + h * 64 + ngd * 16 + lr] =
              (__bf16)(val * inv);
        }
      }
  }
}

extern "C" void kernel_launch(void* const* d_in, const int* in_sizes, int n_in,
                              void* d_out, int out_size, void* d_ws, size_t ws_size,
                              hipStream_t stream) {
  const float* x  = (const float*)d_in[0];
  const float* Wq = (const float*)d_in[1];
  const float* Wk = (const float*)d_in[2];
  const float* Wv = (const float*)d_in[3];
  const float* Wo = (const float*)d_in[4];
  const float* bo = (const float*)d_in[5];
  float* out = (float*)d_out;

  char* ws = (char*)d_ws;
  __bf16* xb    = (__bf16*)(ws);                      // 4096x1024 bf16 (8 MB)
  __bf16* wtqkv = (__bf16*)(ws + (8u << 20));         // 3072x1024 bf16 (6 MB)
  __bf16* wot   = (__bf16*)(ws + (14u << 20));        // 1024x1024 bf16 (2 MB)
  __bf16* qbuf  = (__bf16*)(ws + (16u << 20));        // [bh][pos][d] bf16 (8 MB)
  __bf16* kbuf  = (__bf16*)(ws + (24u << 20));        // swizzled tiles (8 MB)
  __bf16* vbuf  = (__bf16*)(ws + (32u << 20));        // swizzled V^T tiles (8 MB)
  __bf16* ctx   = (__bf16*)(ws + (40u << 20));        // 4096x1024 bf16 (8 MB)

  cvt_f32_bf16_k<<<4096, 256, 0, stream>>>(x, xb, 1048576);
  transpose_w4_k<<<dim3(32, 32, 4), dim3(32, 8), 0, stream>>>(Wq, Wk, Wv, Wo, wtqkv, wot);

  gemm_qkv_k<<<dim3(32, 24), 256, 0, stream>>>(xb, wtqkv, qbuf, kbuf, vbuf);
  attn_fwd_k<<<512, 512, 0, stream>>>(qbuf, kbuf, vbuf, ctx);
  gemm_out_k<<<512, 256, 0, stream>>>(ctx, wot, out, bo);
}

// Round 16
// 100.824 us; speedup vs baseline: 1.0753x; 1.0753x over previous
//
#include <hip/hip_runtime.h>
#include <hip/hip_bf16.h>

// MHA forward: x[2,2048,1024] fp32, Wq/Wk/Wv/Wo [1024,1024] fp32, b_o[1024]
// out = softmax_causal((xWq)(xWk)^T / 8) (xWv) Wo + b_o   (16 heads, d=64)

typedef __bf16 bf16x8 __attribute__((ext_vector_type(8)));
typedef __bf16 bf16x4 __attribute__((ext_vector_type(4)));
typedef float  f32x4  __attribute__((ext_vector_type(4)));

typedef __attribute__((address_space(1))) void gas_void;
typedef __attribute__((address_space(3))) void las_void;

__device__ __forceinline__ void gload_lds16(const void* g, void* l) {
  __builtin_amdgcn_global_load_lds((gas_void*)g, (las_void*)l, 16, 0, 0);
}

#define FULL_DRAIN() asm volatile("s_waitcnt vmcnt(0) lgkmcnt(0)" ::: "memory")
#define SCHED_FENCE() __builtin_amdgcn_sched_barrier(0)

// Q scale: 1/sqrt(64) * log2(e)  (softmax done in exp2 domain)
#define QSCALE 0.18033688011112042f

// ---------------- fused prep: cvt x->bf16 AND 4x W transpose, ONE launch ----------------
// blocks 0..4095: fp32->bf16 convert of x (float4 per thread)
// blocks 4096..8191: W[k][n] fp32 -> Wt[n][k] bf16, z = (bid-4096)>>10
__global__ void prep_all_k(const float* __restrict__ x, __bf16* __restrict__ xb,
                           const float* __restrict__ Wq, const float* __restrict__ Wk,
                           const float* __restrict__ Wv, const float* __restrict__ Wo,
                           __bf16* __restrict__ wtqkv, __bf16* __restrict__ wot) {
  const int bid = blockIdx.x;
  if (bid < 4096) {
    const int i = bid * 256 + threadIdx.x;
    float4 v = ((const float4*)x)[i];
    bf16x4 o = { (__bf16)v.x, (__bf16)v.y, (__bf16)v.z, (__bf16)v.w };
    ((bf16x4*)xb)[i] = o;
    return;
  }
  __shared__ float tile[32][33];
  const int bz = bid - 4096;
  const int z = bz >> 10;
  const float* in = z == 0 ? Wq : z == 1 ? Wk : z == 2 ? Wv : Wo;
  __bf16* out = z < 3 ? wtqkv + (size_t)z * 1048576 : wot;
  const int by = (bz >> 5) & 31, bx = bz & 31;
  const int tx = threadIdx.x & 31, ty = threadIdx.x >> 5;  // 32 x 8
#pragma unroll
  for (int i = 0; i < 4; ++i)
    tile[ty + i * 8][tx] = in[(by * 32 + ty + i * 8) * 1024 + bx * 32 + tx];
  __syncthreads();
#pragma unroll
  for (int i = 0; i < 4; ++i)
    out[(size_t)(bx * 32 + ty + i * 8) * 1024 + by * 32 + tx] = (__bf16)tile[tx][ty + i * 8];
}

// swizzled read from a [rows][32] bf16 tile (64B rows): byte ^= ((row>>1)&3)<<4
__device__ __forceinline__ bf16x8 lds_swz32(const __bf16* base, int row, int cb) {
  const char* p = (const char*)base + row * 64 + (cb ^ (((row >> 1) & 3) << 4));
  return *(const bf16x8*)p;
}

// ---------------- QKV GEMM: 128x128 tile, 3-buffer counted-vmcnt ----------------
// Plain dim3(32,24) grid (round-13 lesson: XCD remap hurt panel locality).
__global__ __launch_bounds__(256) void gemm_qkv_k(
    const __bf16* __restrict__ A, const __bf16* __restrict__ Bt,
    __bf16* __restrict__ qo, __bf16* __restrict__ ko, __bf16* __restrict__ vo)
{
  __shared__ __align__(16) __bf16 As[3][4096];
  __shared__ __align__(16) __bf16 Bs[3][4096];

  const int bm = blockIdx.x, bn = blockIdx.y;

  const int t = threadIdx.x;
  const int l = t & 63;
  const int w = t >> 6;
  const int wr = w >> 1, wc = w & 1;
  const int lr = l & 15;
  const int lkb = (l >> 4) * 16;

  const int swz_el = ((t & 3) * 8) ^ (((t >> 3) & 3) << 3);
  const __bf16* a0 = A + (size_t)(bm * 128 + (t >> 2)) * 1024 + swz_el;
  const __bf16* b0 = Bt + (size_t)(bn * 128 + (t >> 2)) * 1024 + swz_el;

  f32x4 acc[4][4] = {};

#define STAGE(kt_, buf_)                                          \
  do {                                                            \
    const int k0_ = (kt_) * 32;                                   \
    gload_lds16(a0 + k0_, As[buf_] + t * 8);                      \
    gload_lds16(a0 + 64 * 1024 + k0_, As[buf_] + 2048 + t * 8);   \
    gload_lds16(b0 + k0_, Bs[buf_] + t * 8);                      \
    gload_lds16(b0 + 64 * 1024 + k0_, Bs[buf_] + 2048 + t * 8);   \
  } while (0)

  STAGE(0, 0);
  STAGE(1, 1);
  SCHED_FENCE();
  asm volatile("s_waitcnt vmcnt(4)" ::: "memory");
  __builtin_amdgcn_s_barrier();
  SCHED_FENCE();

  int bc = 0, bs = 2;
  for (int kt = 0; kt < 32; ++kt) {
    if (kt < 30) STAGE(kt + 2, bs);
    SCHED_FENCE();

    bf16x8 af[4], bfr[4];
#pragma unroll
    for (int m = 0; m < 4; ++m)
      af[m] = lds_swz32(As[bc], wr * 64 + m * 16 + lr, lkb);
#pragma unroll
    for (int n = 0; n < 4; ++n)
      bfr[n] = lds_swz32(Bs[bc], wc * 64 + n * 16 + lr, lkb);
#pragma unroll
    for (int m = 0; m < 4; ++m)
#pragma unroll
      for (int n = 0; n < 4; ++n)
        acc[m][n] = __builtin_amdgcn_mfma_f32_16x16x32_bf16(af[m], bfr[n], acc[m][n], 0, 0, 0);

    SCHED_FENCE();
    if (kt < 30) asm volatile("s_waitcnt vmcnt(4)" ::: "memory");
    else         asm volatile("s_waitcnt vmcnt(0)" ::: "memory");
    __builtin_amdgcn_s_barrier();
    SCHED_FENCE();
    bc = (bc == 2) ? 0 : bc + 1;
    bs = (bs == 2) ? 0 : bs + 1;
  }
#undef STAGE

#pragma unroll
  for (int m = 0; m < 4; ++m) {
    const int rg = bm * 128 + wr * 64 + m * 16 + (l >> 4) * 4;
#pragma unroll
    for (int n = 0; n < 4; ++n) {
      const int cg = bn * 128 + wc * 64 + n * 16 + lr;
      const int proj = cg >> 10, within = cg & 1023;
      const int h = within >> 6, d = within & 63;
#pragma unroll
      for (int r = 0; r < 4; ++r) {
        const int row = rg + r;
        const int b = row >> 11, pos = row & 2047;
        const int bh = b * 16 + h;
        const float v = acc[m][n][r];
        if (proj == 0) {
          qo[((size_t)bh * 2048 + pos) * 64 + d] = (__bf16)(v * QSCALE);
        } else if (proj == 1) {
          const int tile = pos >> 6, rr = pos & 63;
          const int off = rr * 128 + ((d * 2) ^ ((rr & 7) << 4));
          *(__bf16*)((char*)ko + ((size_t)bh * 32 + tile) * 8192 + off) = (__bf16)v;
        } else {
          const int tile = pos >> 6, cc = pos & 63;
          const int off = d * 128 + ((cc * 2) ^ ((d & 7) << 4));
          *(__bf16*)((char*)vo + ((size_t)bh * 32 + tile) * 8192 + off) = (__bf16)v;
        }
      }
    }
  }
}

// ---------------- out GEMM: 128x64 tile, 2 blocks/CU, 3-buffer ----------------
__global__ __launch_bounds__(256) void gemm_out_k(
    const __bf16* __restrict__ A, const __bf16* __restrict__ Bt,
    float* __restrict__ outf, const float* __restrict__ bias)
{
  __shared__ __align__(16) __bf16 As[3][4096];   // 128x32 per buf
  __shared__ __align__(16) __bf16 Bs[3][2048];   // 64x32 per buf

  const int bid = blockIdx.x;
  const int bm = bid & 31, bn = bid >> 5;        // 32 x 16, plain order

  const int t = threadIdx.x;
  const int l = t & 63;
  const int w = t >> 6;
  const int wr = w >> 1, wc = w & 1;             // 2M x 2N
  const int lr = l & 15;
  const int lkb = (l >> 4) * 16;

  const int swz_el = ((t & 3) * 8) ^ (((t >> 3) & 3) << 3);
  const __bf16* a0 = A + (size_t)(bm * 128 + (t >> 2)) * 1024 + swz_el;
  const __bf16* b0 = Bt + (size_t)(bn * 64 + (t >> 2)) * 1024 + swz_el;

  f32x4 acc[4][2] = {};

#define STAGE(kt_, buf_)                                          \
  do {                                                            \
    const int k0_ = (kt_) * 32;                                   \
    gload_lds16(a0 + k0_, As[buf_] + t * 8);                      \
    gload_lds16(a0 + 64 * 1024 + k0_, As[buf_] + 2048 + t * 8);   \
    gload_lds16(b0 + k0_, Bs[buf_] + t * 8);                      \
  } while (0)

  STAGE(0, 0);
  STAGE(1, 1);
  SCHED_FENCE();
  asm volatile("s_waitcnt vmcnt(3)" ::: "memory");
  __builtin_amdgcn_s_barrier();
  SCHED_FENCE();

  int bc = 0, bs = 2;
  for (int kt = 0; kt < 32; ++kt) {
    if (kt < 30) STAGE(kt + 2, bs);
    SCHED_FENCE();

    bf16x8 af[4], bfr[2];
#pragma unroll
    for (int m = 0; m < 4; ++m)
      af[m] = lds_swz32(As[bc], wr * 64 + m * 16 + lr, lkb);
#pragma unroll
    for (int n = 0; n < 2; ++n)
      bfr[n] = lds_swz32(Bs[bc], wc * 32 + n * 16 + lr, lkb);
#pragma unroll
    for (int m = 0; m < 4; ++m)
#pragma unroll
      for (int n = 0; n < 2; ++n)
        acc[m][n] = __builtin_amdgcn_mfma_f32_16x16x32_bf16(af[m], bfr[n], acc[m][n], 0, 0, 0);

    SCHED_FENCE();
    if (kt < 30) asm volatile("s_waitcnt vmcnt(3)" ::: "memory");
    else         asm volatile("s_waitcnt vmcnt(0)" ::: "memory");
    __builtin_amdgcn_s_barrier();
    SCHED_FENCE();
    bc = (bc == 2) ? 0 : bc + 1;
    bs = (bs == 2) ? 0 : bs + 1;
  }
#undef STAGE

#pragma unroll
  for (int m = 0; m < 4; ++m) {
    const int rg = bm * 128 + wr * 64 + m * 16 + (l >> 4) * 4;
#pragma unroll
    for (int n = 0; n < 2; ++n) {
      const int cg = bn * 64 + wc * 32 + n * 16 + lr;
#pragma unroll
      for (int r = 0; r < 4; ++r)
        outf[(size_t)(rg + r) * 1024 + cg] = acc[m][n][r] + bias[cg];
    }
  }
}

// swizzled LDS fragment read: tile row stride 128 B, byte ^= (row&7)<<4
__device__ __forceinline__ bf16x8 lds_swz(const __bf16* base, int row, int cb) {
  const char* p = (const char*)base + row * 128 + (cb ^ ((row & 7) << 4));
  return *(const bf16x8*)p;
}

// ---------------- flash attention (causal), head_dim=64 ----------------
// ROUND-14 VERSION (proven ~34us): 512 blocks x 512 threads, q-tile 128,
// kv-tile 64, 8 waves as (qb = w&3: 32 q-rows) x (kvh = w>>2: 32-kv half).
// Double-buffered K/V with per-iter FULL_DRAIN: the drain is hidden by
// 3-blocks/CU TLP (round-15 lesson: a 3rd buffer for counted-vmcnt costs
// 16KB LDS -> 2 blocks/CU -> net LOSS. LDS budget buys TLP; TLP wins here.)
__global__ __launch_bounds__(512) void attn_fwd_k(
    const __bf16* __restrict__ Q, const __bf16* __restrict__ K,
    const __bf16* __restrict__ V, __bf16* __restrict__ ctx)
{
  __shared__ __align__(16) char smem[53760];
  __bf16* Kbuf = (__bf16*)smem;                    // [2][4096] bf16, 16KB
  __bf16* Vbuf = (__bf16*)(smem + 16384);          // [2][4096] bf16, 16KB
  __bf16* PsB  = (__bf16*)(smem + 32768);          // [8][32*40] bf16, 20KB
  float*  LsX  = (float*)(smem + 53248);           // [4][32] f32, 512B
  float*  xch  = (float*)smem;                     // 8192 f32 (aliases K/V bufs)

  const int n = blockIdx.x;
  const int bh = (n & 255) >> 3;
  const int pp = n & 7;
  const int qt = (n >> 8) ? pp : 15 - pp;   // q-tile of 128 rows
  const int nkt = 2 * qt + 2;               // kv tiles of 64

  const int t = threadIdx.x, l = t & 63, w = t >> 6;   // w = 0..7
  const int lr = l & 15, lg = l >> 4;
  const int qb = w & 3;
  const int kvh = w >> 2;

  const __bf16* qptr = Q + (size_t)bh * 131072;
  const __bf16* kptr = K + (size_t)bh * 131072;
  const __bf16* vptr = V + (size_t)bh * 131072;
  __bf16* Ps = PsB + w * 1280;

  bf16x8 qf[2][2];
#pragma unroll
  for (int m = 0; m < 2; ++m)
#pragma unroll
    for (int h2 = 0; h2 < 2; ++h2)
      qf[m][h2] = *(const bf16x8*)(qptr + (size_t)(qt * 128 + qb * 32 + m * 16 + lr) * 64 + h2 * 32 + lg * 8);

  f32x4 o[2][4] = {};
  f32x4 lsum[2] = {};

  gload_lds16(kptr + t * 8, Kbuf + t * 8);
  gload_lds16(vptr + t * 8, Vbuf + t * 8);
  FULL_DRAIN();
  __syncthreads();
  SCHED_FENCE();

  for (int kt = 0; kt < nkt; ++kt) {
    const int cur = kt & 1;
    if (kt + 1 < nkt) {
      gload_lds16(kptr + (kt + 1) * 4096 + t * 8, Kbuf + (cur ^ 1) * 4096 + t * 8);
      gload_lds16(vptr + (kt + 1) * 4096 + t * 8, Vbuf + (cur ^ 1) * 4096 + t * 8);
    }
    SCHED_FENCE();
    const __bf16* Kb = Kbuf + cur * 4096;
    const __bf16* Vb = Vbuf + cur * 4096;

    bf16x8 kf[2][2];
#pragma unroll
    for (int ng = 0; ng < 2; ++ng)
#pragma unroll
      for (int h2 = 0; h2 < 2; ++h2)
        kf[ng][h2] = lds_swz(Kb, kvh * 32 + ng * 16 + lr, h2 * 64 + lg * 16);

    f32x4 s[2][2];
#pragma unroll
    for (int m = 0; m < 2; ++m)
#pragma unroll
      for (int ng = 0; ng < 2; ++ng) {
        f32x4 z = {};
        z = __builtin_amdgcn_mfma_f32_16x16x32_bf16(qf[m][0], kf[ng][0], z, 0, 0, 0);
        s[m][ng] = __builtin_amdgcn_mfma_f32_16x16x32_bf16(qf[m][1], kf[ng][1], z, 0, 0, 0);
      }

    if (kt >= 2 * qt) {
#pragma unroll
      for (int m = 0; m < 2; ++m) {
        const int qpos = qt * 128 + qb * 32 + m * 16 + lg * 4;
#pragma unroll
        for (int ng = 0; ng < 2; ++ng) {
          const int kv = kt * 64 + kvh * 32 + ng * 16 + lr;
#pragma unroll
          for (int r = 0; r < 4; ++r)
            if (kv > qpos + r) s[m][ng][r] = -1e30f;
        }
      }
    }

#pragma unroll
    for (int m = 0; m < 2; ++m)
#pragma unroll
      for (int ng = 0; ng < 2; ++ng)
#pragma unroll
        for (int r = 0; r < 4; ++r) {
          const float p = __builtin_amdgcn_exp2f(s[m][ng][r]);
          lsum[m][r] += p;
          Ps[(m * 16 + lg * 4 + r) * 40 + ng * 16 + lr] = (__bf16)p;
        }

    asm volatile("s_waitcnt lgkmcnt(0)" ::: "memory");
    SCHED_FENCE();

    bf16x8 pf[2];
#pragma unroll
    for (int m = 0; m < 2; ++m)
      pf[m] = *(const bf16x8*)(Ps + (m * 16 + lr) * 40 + lg * 8);
    bf16x8 vf[4];
#pragma unroll
    for (int ngd = 0; ngd < 4; ++ngd)
      vf[ngd] = lds_swz(Vb, ngd * 16 + lr, kvh * 64 + lg * 16);
#pragma unroll
    for (int m = 0; m < 2; ++m)
#pragma unroll
      for (int ngd = 0; ngd < 4; ++ngd)
        o[m][ngd] = __builtin_amdgcn_mfma_f32_16x16x32_bf16(pf[m], vf[ngd], o[m][ngd], 0, 0, 0);

    FULL_DRAIN();
    __syncthreads();
    SCHED_FENCE();
  }

#pragma unroll
  for (int m = 0; m < 2; ++m)
#pragma unroll
    for (int r = 0; r < 4; ++r) {
      float v = lsum[m][r];
      v += __shfl_xor(v, 1);
      v += __shfl_xor(v, 2);
      v += __shfl_xor(v, 4);
      v += __shfl_xor(v, 8);
      lsum[m][r] = v;
    }

  if (kvh == 1) {
#pragma unroll
    for (int m = 0; m < 2; ++m)
#pragma unroll
      for (int ngd = 0; ngd < 4; ++ngd)
#pragma unroll
        for (int r = 0; r < 4; ++r)
          xch[qb * 2048 + (m * 16 + lg * 4 + r) * 64 + ngd * 16 + lr] = o[m][ngd][r];
    if (lr == 0) {
#pragma unroll
      for (int m = 0; m < 2; ++m)
#pragma unroll
        for (int r = 0; r < 4; ++r)
          LsX[qb * 32 + m * 16 + lg * 4 + r] = lsum[m][r];
    }
  }
  FULL_DRAIN();
  __syncthreads();
  SCHED_FENCE();

  if (kvh == 0) {
    const int b_ = bh >> 4, h = bh & 15;
#pragma unroll
    for (int m = 0; m < 2; ++m)
#pragma unroll
      for (int r = 0; r < 4; ++r) {
        const float sum = lsum[m][r] + LsX[qb * 32 + m * 16 + lg * 4 + r];
        const float inv = 1.0f / sum;
        const int pos = qt * 128 + qb * 32 + m * 16 + lg * 4 + r;
#pragma unroll
        for (int ngd = 0; ngd < 4; ++ngd) {
          const float val = o[m][ngd][r] +
              xch[qb * 2048 + (m * 16 + lg * 4 + r) * 64 + ngd * 16 + lr];
          ctx[((size_t)(b_ * 2048 + pos)) * 1024 + h * 64 + ngd * 16 + lr] =
              (__bf16)(val * inv);
        }
      }
  }
}

extern "C" void kernel_launch(void* const* d_in, const int* in_sizes, int n_in,
                              void* d_out, int out_size, void* d_ws, size_t ws_size,
                              hipStream_t stream) {
  const float* x  = (const float*)d_in[0];
  const float* Wq = (const float*)d_in[1];
  const float* Wk = (const float*)d_in[2];
  const float* Wv = (const float*)d_in[3];
  const float* Wo = (const float*)d_in[4];
  const float* bo = (const float*)d_in[5];
  float* out = (float*)d_out;

  char* ws = (char*)d_ws;
  __bf16* xb    = (__bf16*)(ws);                      // 4096x1024 bf16 (8 MB)
  __bf16* wtqkv = (__bf16*)(ws + (8u << 20));         // 3072x1024 bf16 (6 MB)
  __bf16* wot   = (__bf16*)(ws + (14u << 20));        // 1024x1024 bf16 (2 MB)
  __bf16* qbuf  = (__bf16*)(ws + (16u << 20));        // [bh][pos][d] bf16 (8 MB)
  __bf16* kbuf  = (__bf16*)(ws + (24u << 20));        // swizzled tiles (8 MB)
  __bf16* vbuf  = (__bf16*)(ws + (32u << 20));        // swizzled V^T tiles (8 MB)
  __bf16* ctx   = (__bf16*)(ws + (40u << 20));        // 4096x1024 bf16 (8 MB)

  prep_all_k<<<8192, 256, 0, stream>>>(x, xb, Wq, Wk, Wv, Wo, wtqkv, wot);
  gemm_qkv_k<<<dim3(32, 24), 256, 0, stream>>>(xb, wtqkv, qbuf, kbuf, vbuf);
  attn_fwd_k<<<512, 512, 0, stream>>>(qbuf, kbuf, vbuf, ctx);
  gemm_out_k<<<512, 256, 0, stream>>>(ctx, wot, out, bo);
}